// Round 1
// baseline (1252.389 us; speedup 1.0000x reference)
//
#include <hip/hip_runtime.h>
#include <hip/hip_bf16.h>
#include <math.h>

#define TT 1024
#define HH 2048
#define EE 32
#define II 1024
#define MT 16

// ---------------- router: mix = x @ w_qkv^T  [T, 96] ----------------
__global__ void k_router_mix(const float* __restrict__ x,
                             const float* __restrict__ wqkv,
                             float* __restrict__ mix) {
    __shared__ float xs[HH];
    const int t = blockIdx.x;
    const float4* xr = (const float4*)(x + (size_t)t * HH);
    float4* xs4 = (float4*)xs;
    for (int i = threadIdx.x; i < HH / 4; i += blockDim.x) xs4[i] = xr[i];
    __syncthreads();
    const int j = threadIdx.x;
    if (j < 3 * EE) {
        const float4* wr = (const float4*)(wqkv + (size_t)j * HH);
        float acc = 0.f;
        for (int i = 0; i < HH / 4; ++i) {
            float4 w = wr[i];
            float4 a = xs4[i];
            acc += a.x * w.x + a.y * w.y + a.z * w.z + a.w * w.w;
        }
        mix[t * 96 + j] = acc;
    }
}

// ---------------- router: attention logits + top-2 + scatter ----------------
__global__ void k_router_attn(const float* __restrict__ mix,
                              int* __restrict__ cnt,
                              int* __restrict__ tok_list,
                              float* __restrict__ wgt_list) {
    const int t = blockIdx.x;
    __shared__ float kk[EE], vv[EE], lg[EE];
    const int lane = threadIdx.x;
    if (lane < EE) {
        kk[lane] = mix[t * 96 + EE + lane];
        vv[lane] = mix[t * 96 + 2 * EE + lane];
    }
    __syncthreads();
    if (lane < EE) {
        float q = mix[t * 96 + lane];
        float m = -1e30f;
        for (int f = 0; f < EE; ++f) m = fmaxf(m, q * kk[f]);
        float s = 0.f, a = 0.f;
        for (int f = 0; f < EE; ++f) {
            float ex = expf(q * kk[f] - m);
            s += ex;
            a += ex * vv[f];
        }
        lg[lane] = a / s;
    }
    __syncthreads();
    if (lane == 0) {
        // top-1 (strict > => first index on tie, matches jax.lax.top_k)
        int b0 = 0; float v0 = lg[0];
        for (int e2 = 1; e2 < EE; ++e2)
            if (lg[e2] > v0) { v0 = lg[e2]; b0 = e2; }
        int b1 = -1; float v1 = -1e30f;
        for (int e2 = 0; e2 < EE; ++e2)
            if (e2 != b0 && lg[e2] > v1) { v1 = lg[e2]; b1 = e2; }
        // softmax over the two (v0 >= v1)
        float ex = expf(v1 - v0);
        float w0 = 1.f / (1.f + ex);
        float w1 = ex / (1.f + ex);
        int p0 = atomicAdd(&cnt[b0], 1);
        tok_list[b0 * TT + p0] = t * 2 + 0;
        wgt_list[b0 * TT + p0] = w0;
        int p1 = atomicAdd(&cnt[b1], 1);
        tok_list[b1 * TT + p1] = t * 2 + 1;
        wgt_list[b1 * TT + p1] = w1;
    }
}

// ---------------- phase 1: act[t,slot,i] = silu(gate)*up*w ----------------
// grid (II/64, EE); block handles expert e, i-range [i0, i0+64)
__global__ __launch_bounds__(256) void k_phase1(
    const float* __restrict__ x, const float* __restrict__ w1,
    const int* __restrict__ cnt, const int* __restrict__ tok_list,
    const float* __restrict__ wgt_list, float* __restrict__ act) {
    const int e = blockIdx.y;
    const int i0 = blockIdx.x * 64;
    const int M = cnt[e];
    if (M == 0) return;
    __shared__ float As[MT][34];
    __shared__ float Bs[128][34];   // rows 0..63 gate, 64..127 up
    __shared__ int   ts[MT];
    __shared__ float tw[MT];
    const float* w1e = w1 + (size_t)e * (2 * II) * HH;
    const int tid = threadIdx.x;
    const int rt = tid >> 5;        // 0..7 -> token pair
    const int ct = tid & 31;        // 0..31 -> column

    for (int m0 = 0; m0 < M; m0 += MT) {
        __syncthreads();
        if (tid < MT) {
            int mrow = m0 + tid;
            if (mrow < M) {
                ts[tid] = tok_list[e * TT + mrow];
                tw[tid] = wgt_list[e * TT + mrow];
            } else ts[tid] = -1;
        }
        __syncthreads();
        float acc[2][4];
#pragma unroll
        for (int a = 0; a < 2; ++a)
#pragma unroll
            for (int b = 0; b < 4; ++b) acc[a][b] = 0.f;

        for (int kc = 0; kc < HH; kc += 32) {
            {   // stage A: 16 tokens x 32 k
                int idx = tid * 2;
                int r = idx >> 5;
                int c = idx & 31;
                float2 av = make_float2(0.f, 0.f);
                int entry = ts[r];
                if (entry >= 0)
                    av = *(const float2*)(x + (size_t)(entry >> 1) * HH + kc + c);
                As[r][c] = av.x;
                As[r][c + 1] = av.y;
            }
#pragma unroll
            for (int q = 0; q < 4; ++q) {  // stage B: 128 rows x 32 k
                int idx = tid + q * 256;
                int row = idx >> 3;
                int f4 = (idx & 7) * 4;
                const float* src = (row < 64)
                    ? (w1e + (size_t)(i0 + row) * HH + kc + f4)
                    : (w1e + (size_t)(II + i0 + (row - 64)) * HH + kc + f4);
                float4 v = *(const float4*)src;
                *(float2*)&Bs[row][f4]     = make_float2(v.x, v.y);
                *(float2*)&Bs[row][f4 + 2] = make_float2(v.z, v.w);
            }
            __syncthreads();
#pragma unroll
            for (int kk = 0; kk < 32; kk += 2) {
                float2 a0 = *(const float2*)&As[rt * 2 + 0][kk];
                float2 a1 = *(const float2*)&As[rt * 2 + 1][kk];
                float2 b0 = *(const float2*)&Bs[ct][kk];
                float2 b1 = *(const float2*)&Bs[ct + 32][kk];
                float2 b2 = *(const float2*)&Bs[ct + 64][kk];
                float2 b3 = *(const float2*)&Bs[ct + 96][kk];
                acc[0][0] += a0.x * b0.x + a0.y * b0.y;
                acc[0][1] += a0.x * b1.x + a0.y * b1.y;
                acc[0][2] += a0.x * b2.x + a0.y * b2.y;
                acc[0][3] += a0.x * b3.x + a0.y * b3.y;
                acc[1][0] += a1.x * b0.x + a1.y * b0.y;
                acc[1][1] += a1.x * b1.x + a1.y * b1.y;
                acc[1][2] += a1.x * b2.x + a1.y * b2.y;
                acc[1][3] += a1.x * b3.x + a1.y * b3.y;
            }
            __syncthreads();
        }
        // epilogue: act[entry, i] = silu(gate)*up*w
#pragma unroll
        for (int rr = 0; rr < 2; ++rr) {
            int r = rt * 2 + rr;
            int entry = ts[r];
            if (entry >= 0) {
                float w = tw[r];
                float g0 = acc[rr][0], g1 = acc[rr][1];
                float u0 = acc[rr][2], u1 = acc[rr][3];
                float s0 = (g0 / (1.f + expf(-g0))) * u0 * w;
                float s1 = (g1 / (1.f + expf(-g1))) * u1 * w;
                float* ap = act + (size_t)entry * II + i0;
                ap[ct] = s0;
                ap[ct + 32] = s1;
            }
        }
    }
}

// ---------------- phase 2: out[t,h] += act[t,slot,:] . w2[e][h,:] ----------------
// grid (HH/128, EE); block handles expert e, h-range [h0, h0+128)
__global__ __launch_bounds__(256) void k_phase2(
    const float* __restrict__ act, const float* __restrict__ w2,
    const int* __restrict__ cnt, const int* __restrict__ tok_list,
    float* __restrict__ out) {
    const int e = blockIdx.y;
    const int h0 = blockIdx.x * 128;
    const int M = cnt[e];
    if (M == 0) return;
    __shared__ float As[MT][34];
    __shared__ float Bs[128][34];
    __shared__ int ts[MT];
    const float* w2e = w2 + (size_t)e * HH * II;
    const int tid = threadIdx.x;
    const int rt = tid >> 5;
    const int ct = tid & 31;

    for (int m0 = 0; m0 < M; m0 += MT) {
        __syncthreads();
        if (tid < MT) {
            int mrow = m0 + tid;
            ts[tid] = (mrow < M) ? tok_list[e * TT + mrow] : -1;
        }
        __syncthreads();
        float acc[2][4];
#pragma unroll
        for (int a = 0; a < 2; ++a)
#pragma unroll
            for (int b = 0; b < 4; ++b) acc[a][b] = 0.f;

        for (int kc = 0; kc < II; kc += 32) {
            {   // stage A from act (row index IS the packed entry)
                int idx = tid * 2;
                int r = idx >> 5;
                int c = idx & 31;
                float2 av = make_float2(0.f, 0.f);
                int entry = ts[r];
                if (entry >= 0)
                    av = *(const float2*)(act + (size_t)entry * II + kc + c);
                As[r][c] = av.x;
                As[r][c + 1] = av.y;
            }
#pragma unroll
            for (int q = 0; q < 4; ++q) {  // stage B: w2[e][h0+row][kc..kc+32)
                int idx = tid + q * 256;
                int row = idx >> 3;
                int f4 = (idx & 7) * 4;
                float4 v = *(const float4*)(w2e + (size_t)(h0 + row) * II + kc + f4);
                *(float2*)&Bs[row][f4]     = make_float2(v.x, v.y);
                *(float2*)&Bs[row][f4 + 2] = make_float2(v.z, v.w);
            }
            __syncthreads();
#pragma unroll
            for (int kk = 0; kk < 32; kk += 2) {
                float2 a0 = *(const float2*)&As[rt * 2 + 0][kk];
                float2 a1 = *(const float2*)&As[rt * 2 + 1][kk];
                float2 b0 = *(const float2*)&Bs[ct][kk];
                float2 b1 = *(const float2*)&Bs[ct + 32][kk];
                float2 b2 = *(const float2*)&Bs[ct + 64][kk];
                float2 b3 = *(const float2*)&Bs[ct + 96][kk];
                acc[0][0] += a0.x * b0.x + a0.y * b0.y;
                acc[0][1] += a0.x * b1.x + a0.y * b1.y;
                acc[0][2] += a0.x * b2.x + a0.y * b2.y;
                acc[0][3] += a0.x * b3.x + a0.y * b3.y;
                acc[1][0] += a1.x * b0.x + a1.y * b0.y;
                acc[1][1] += a1.x * b1.x + a1.y * b1.y;
                acc[1][2] += a1.x * b2.x + a1.y * b2.y;
                acc[1][3] += a1.x * b3.x + a1.y * b3.y;
            }
            __syncthreads();
        }
        // epilogue: accumulate into out (token appears in 2 expert lists)
#pragma unroll
        for (int rr = 0; rr < 2; ++rr) {
            int r = rt * 2 + rr;
            int entry = ts[r];
            if (entry >= 0) {
                int t = entry >> 1;
                float* op = out + (size_t)t * HH + h0;
                atomicAdd(&op[ct],      acc[rr][0]);
                atomicAdd(&op[ct + 32], acc[rr][1]);
                atomicAdd(&op[ct + 64], acc[rr][2]);
                atomicAdd(&op[ct + 96], acc[rr][3]);
            }
        }
    }
}

extern "C" void kernel_launch(void* const* d_in, const int* in_sizes, int n_in,
                              void* d_out, int out_size, void* d_ws, size_t ws_size,
                              hipStream_t stream) {
    const float* x    = (const float*)d_in[0];
    const float* wqkv = (const float*)d_in[1];
    const float* w1   = (const float*)d_in[2];
    const float* w2   = (const float*)d_in[3];
    float* out = (float*)d_out;

    char* ws = (char*)d_ws;
    float* mix      = (float*)(ws);                 // 1024*96*4   = 393216 B
    float* wgt_list = (float*)(ws + 393216);        // 32*1024*4   = 131072 B
    float* act      = (float*)(ws + 524288);        // 1024*2*1024*4 = 8388608 B
    int*   tok_list = (int*)  (ws + 8912896);       // 32*1024*4   = 131072 B
    int*   cnt      = (int*)  (ws + 9043968);       // 32*4 -> pad 128 B

    hipMemsetAsync(cnt, 0, 128, stream);
    hipMemsetAsync(out, 0, (size_t)out_size * sizeof(float), stream);

    k_router_mix<<<TT, 128, 0, stream>>>(x, wqkv, mix);
    k_router_attn<<<TT, 64, 0, stream>>>(mix, cnt, tok_list, wgt_list);
    k_phase1<<<dim3(II / 64, EE), 256, 0, stream>>>(x, w1, cnt, tok_list, wgt_list, act);
    k_phase2<<<dim3(HH / 128, EE), 256, 0, stream>>>(act, w2, cnt, tok_list, out);
}

// Round 2
// 345.043 us; speedup vs baseline: 3.6297x; 3.6297x over previous
//
#include <hip/hip_runtime.h>
#include <hip/hip_bf16.h>
#include <math.h>

#define TT 1024
#define HH 2048
#define EE 32
#define II 1024
#define BK 64
#define SA 72   // LDS row stride in bf16 elems (64 + 8 pad -> 2-way bank alias only)

typedef __attribute__((ext_vector_type(8))) short bf16x8;
typedef __attribute__((ext_vector_type(8))) unsigned short ushort8;
typedef __attribute__((ext_vector_type(4))) float f32x4;

__device__ __forceinline__ unsigned short f2b(float f) {
    union { float f; unsigned u; } c; c.f = f;
    unsigned r = c.u + 0x7FFFu + ((c.u >> 16) & 1u);   // RNE to bf16
    return (unsigned short)(r >> 16);
}
__device__ __forceinline__ float b2f(unsigned short u) {
    union { unsigned u; float f; } c; c.u = ((unsigned)u) << 16;
    return c.f;
}

// ---------------- router: mix = x @ w_qkv^T  [T, 96] ----------------
__global__ void k_router_mix(const float* __restrict__ x,
                             const float* __restrict__ wqkv,
                             float* __restrict__ mix) {
    __shared__ float xs[HH];
    const int t = blockIdx.x;
    const float4* xr = (const float4*)(x + (size_t)t * HH);
    float4* xs4 = (float4*)xs;
    for (int i = threadIdx.x; i < HH / 4; i += blockDim.x) xs4[i] = xr[i];
    __syncthreads();
    const int j = threadIdx.x;
    if (j < 3 * EE) {
        const float4* wr = (const float4*)(wqkv + (size_t)j * HH);
        float acc = 0.f;
        for (int i = 0; i < HH / 4; ++i) {
            float4 w = wr[i];
            float4 a = xs4[i];
            acc += a.x * w.x + a.y * w.y + a.z * w.z + a.w * w.w;
        }
        mix[t * 96 + j] = acc;
    }
}

// ---------------- router: attention logits + top-2 + scatter ----------------
__global__ void k_router_attn(const float* __restrict__ mix,
                              int* __restrict__ cnt,
                              int* __restrict__ tok_list,
                              float* __restrict__ wgt_list) {
    const int t = blockIdx.x;
    __shared__ float kk[EE], vv[EE], lg[EE];
    const int lane = threadIdx.x;
    if (lane < EE) {
        kk[lane] = mix[t * 96 + EE + lane];
        vv[lane] = mix[t * 96 + 2 * EE + lane];
    }
    __syncthreads();
    if (lane < EE) {
        float q = mix[t * 96 + lane];
        float m = -1e30f;
        for (int f = 0; f < EE; ++f) m = fmaxf(m, q * kk[f]);
        float s = 0.f, a = 0.f;
        for (int f = 0; f < EE; ++f) {
            float ex = expf(q * kk[f] - m);
            s += ex;
            a += ex * vv[f];
        }
        lg[lane] = a / s;
    }
    __syncthreads();
    if (lane == 0) {
        int b0 = 0; float v0 = lg[0];
        for (int e2 = 1; e2 < EE; ++e2)
            if (lg[e2] > v0) { v0 = lg[e2]; b0 = e2; }
        int b1 = -1; float v1 = -1e30f;
        for (int e2 = 0; e2 < EE; ++e2)
            if (e2 != b0 && lg[e2] > v1) { v1 = lg[e2]; b1 = e2; }
        float ex = expf(v1 - v0);
        float w0 = 1.f / (1.f + ex);
        float w1 = ex / (1.f + ex);
        int p0 = atomicAdd(&cnt[b0], 1);
        tok_list[b0 * TT + p0] = t * 2 + 0;
        wgt_list[b0 * TT + p0] = w0;
        int p1 = atomicAdd(&cnt[b1], 1);
        tok_list[b1 * TT + p1] = t * 2 + 1;
        wgt_list[b1 * TT + p1] = w1;
    }
}

// ---------------- gemm1: gu[entry, 0:2I] = x[tok] @ w1[e]^T  (bf16 MFMA) ----------------
// grid (2I/128, E, 8 m-chunks); block = 256 thr = 4 waves (2m x 2n), tile 128x128, BK=64
__global__ __launch_bounds__(256) void k_gemm1(
    const float* __restrict__ x, const float* __restrict__ w1,
    const int* __restrict__ cnt, const int* __restrict__ tok_list,
    unsigned short* __restrict__ gu) {
    const int e = blockIdx.y;
    const int M = cnt[e];
    const int m0 = blockIdx.z * 128;
    if (m0 >= M) return;
    const int n0 = blockIdx.x * 128;

    __shared__ __align__(16) unsigned short As[128 * SA];
    __shared__ __align__(16) unsigned short Bs[128 * SA];
    __shared__ int ts[128];

    const int tid = threadIdx.x;
    if (tid < 128) {
        int mr = m0 + tid;
        ts[tid] = (mr < M) ? tok_list[e * TT + mr] : -1;
    }
    __syncthreads();

    const float* w1e = w1 + (size_t)e * (2 * II) * HH;
    const int wid = tid >> 6;
    const int lane = tid & 63;
    const int wm = wid >> 1, wn = wid & 1;
    const int fr = lane & 15;
    const int kg = lane >> 4;

    f32x4 acc[4][4];
#pragma unroll
    for (int i = 0; i < 4; ++i)
#pragma unroll
        for (int j = 0; j < 4; ++j) acc[i][j] = (f32x4){0.f, 0.f, 0.f, 0.f};

    for (int k0 = 0; k0 < HH; k0 += BK) {
        __syncthreads();
        // stage A: 128 tokens x 64 k, fp32 -> bf16
#pragma unroll
        for (int q = 0; q < 4; ++q) {
            int p = tid + q * 256;
            int row = p >> 3;
            int c8 = (p & 7) * 8;
            float4 v0 = {0.f, 0.f, 0.f, 0.f}, v1 = {0.f, 0.f, 0.f, 0.f};
            int entry = ts[row];
            if (entry >= 0) {
                const float* src = x + (size_t)(entry >> 1) * HH + k0 + c8;
                v0 = *(const float4*)src;
                v1 = *(const float4*)(src + 4);
            }
            ushort8 pk;
            pk[0] = f2b(v0.x); pk[1] = f2b(v0.y); pk[2] = f2b(v0.z); pk[3] = f2b(v0.w);
            pk[4] = f2b(v1.x); pk[5] = f2b(v1.y); pk[6] = f2b(v1.z); pk[7] = f2b(v1.w);
            *(ushort8*)&As[row * SA + c8] = pk;
        }
        // stage B: w1 rows [n0, n0+128) x 64 k
#pragma unroll
        for (int q = 0; q < 4; ++q) {
            int p = tid + q * 256;
            int row = p >> 3;
            int c8 = (p & 7) * 8;
            const float* src = w1e + (size_t)(n0 + row) * HH + k0 + c8;
            float4 v0 = *(const float4*)src;
            float4 v1 = *(const float4*)(src + 4);
            ushort8 pk;
            pk[0] = f2b(v0.x); pk[1] = f2b(v0.y); pk[2] = f2b(v0.z); pk[3] = f2b(v0.w);
            pk[4] = f2b(v1.x); pk[5] = f2b(v1.y); pk[6] = f2b(v1.z); pk[7] = f2b(v1.w);
            *(ushort8*)&Bs[row * SA + c8] = pk;
        }
        __syncthreads();
#pragma unroll
        for (int kh = 0; kh < 2; ++kh) {
            const int kb = kh * 32 + kg * 8;
            bf16x8 a[4], b[4];
#pragma unroll
            for (int i = 0; i < 4; ++i)
                a[i] = *(const bf16x8*)&As[(wm * 64 + i * 16 + fr) * SA + kb];
#pragma unroll
            for (int j = 0; j < 4; ++j)
                b[j] = *(const bf16x8*)&Bs[(wn * 64 + j * 16 + fr) * SA + kb];
#pragma unroll
            for (int i = 0; i < 4; ++i)
#pragma unroll
                for (int j = 0; j < 4; ++j)
                    acc[i][j] = __builtin_amdgcn_mfma_f32_16x16x32_bf16(a[i], b[j], acc[i][j], 0, 0, 0);
        }
    }
    // epilogue: store bf16 raw gate/up
#pragma unroll
    for (int mi = 0; mi < 4; ++mi) {
#pragma unroll
        for (int reg = 0; reg < 4; ++reg) {
            int m = wm * 64 + mi * 16 + kg * 4 + reg;
            int entry = ts[m];
            if (entry < 0) continue;
            unsigned short* dst = gu + (size_t)entry * (2 * II) + n0 + wn * 64;
#pragma unroll
            for (int ni = 0; ni < 4; ++ni)
                dst[ni * 16 + fr] = f2b(acc[mi][ni][reg]);
        }
    }
}

// ---------------- gemm2: out[t] += (silu(gate)*up*w) @ w2[e]^T  (bf16 MFMA) ----------------
// grid (H/128, E, 8 m-chunks)
__global__ __launch_bounds__(256) void k_gemm2(
    const unsigned short* __restrict__ gu, const float* __restrict__ w2,
    const int* __restrict__ cnt, const int* __restrict__ tok_list,
    const float* __restrict__ wgt_list, float* __restrict__ out) {
    const int e = blockIdx.y;
    const int M = cnt[e];
    const int m0 = blockIdx.z * 128;
    if (m0 >= M) return;
    const int n0 = blockIdx.x * 128;

    __shared__ __align__(16) unsigned short As[128 * SA];
    __shared__ __align__(16) unsigned short Bs[128 * SA];
    __shared__ int ts[128];
    __shared__ float tw[128];

    const int tid = threadIdx.x;
    if (tid < 128) {
        int mr = m0 + tid;
        if (mr < M) {
            ts[tid] = tok_list[e * TT + mr];
            tw[tid] = wgt_list[e * TT + mr];
        } else { ts[tid] = -1; tw[tid] = 0.f; }
    }
    __syncthreads();

    const float* w2e = w2 + (size_t)e * HH * II;
    const int wid = tid >> 6;
    const int lane = tid & 63;
    const int wm = wid >> 1, wn = wid & 1;
    const int fr = lane & 15;
    const int kg = lane >> 4;

    f32x4 acc[4][4];
#pragma unroll
    for (int i = 0; i < 4; ++i)
#pragma unroll
        for (int j = 0; j < 4; ++j) acc[i][j] = (f32x4){0.f, 0.f, 0.f, 0.f};

    for (int k0 = 0; k0 < II; k0 += BK) {
        __syncthreads();
        // stage A: act = silu(gate)*up*w from gu (bf16 in, bf16 out)
#pragma unroll
        for (int q = 0; q < 4; ++q) {
            int p = tid + q * 256;
            int row = p >> 3;
            int c8 = (p & 7) * 8;
            ushort8 pk = {0, 0, 0, 0, 0, 0, 0, 0};
            int entry = ts[row];
            if (entry >= 0) {
                const ushort8 g8 = *(const ushort8*)(gu + (size_t)entry * (2 * II) + k0 + c8);
                const ushort8 u8 = *(const ushort8*)(gu + (size_t)entry * (2 * II) + II + k0 + c8);
                float w = tw[row];
#pragma unroll
                for (int j = 0; j < 8; ++j) {
                    float g = b2f(g8[j]);
                    float u = b2f(u8[j]);
                    float s = g / (1.f + __expf(-g));
                    pk[j] = f2b(s * u * w);
                }
            }
            *(ushort8*)&As[row * SA + c8] = pk;
        }
        // stage B: w2 rows [n0, n0+128) x 64 k
#pragma unroll
        for (int q = 0; q < 4; ++q) {
            int p = tid + q * 256;
            int row = p >> 3;
            int c8 = (p & 7) * 8;
            const float* src = w2e + (size_t)(n0 + row) * II + k0 + c8;
            float4 v0 = *(const float4*)src;
            float4 v1 = *(const float4*)(src + 4);
            ushort8 pk;
            pk[0] = f2b(v0.x); pk[1] = f2b(v0.y); pk[2] = f2b(v0.z); pk[3] = f2b(v0.w);
            pk[4] = f2b(v1.x); pk[5] = f2b(v1.y); pk[6] = f2b(v1.z); pk[7] = f2b(v1.w);
            *(ushort8*)&Bs[row * SA + c8] = pk;
        }
        __syncthreads();
#pragma unroll
        for (int kh = 0; kh < 2; ++kh) {
            const int kb = kh * 32 + kg * 8;
            bf16x8 a[4], b[4];
#pragma unroll
            for (int i = 0; i < 4; ++i)
                a[i] = *(const bf16x8*)&As[(wm * 64 + i * 16 + fr) * SA + kb];
#pragma unroll
            for (int j = 0; j < 4; ++j)
                b[j] = *(const bf16x8*)&Bs[(wn * 64 + j * 16 + fr) * SA + kb];
#pragma unroll
            for (int i = 0; i < 4; ++i)
#pragma unroll
                for (int j = 0; j < 4; ++j)
                    acc[i][j] = __builtin_amdgcn_mfma_f32_16x16x32_bf16(a[i], b[j], acc[i][j], 0, 0, 0);
        }
    }
    // epilogue: accumulate into out (each token is in 2 expert lists -> atomic)
#pragma unroll
    for (int mi = 0; mi < 4; ++mi) {
#pragma unroll
        for (int reg = 0; reg < 4; ++reg) {
            int m = wm * 64 + mi * 16 + kg * 4 + reg;
            int entry = ts[m];
            if (entry < 0) continue;
            int t = entry >> 1;
            float* op = out + (size_t)t * HH + n0 + wn * 64;
#pragma unroll
            for (int ni = 0; ni < 4; ++ni)
                atomicAdd(&op[ni * 16 + fr], acc[mi][ni][reg]);
        }
    }
}

extern "C" void kernel_launch(void* const* d_in, const int* in_sizes, int n_in,
                              void* d_out, int out_size, void* d_ws, size_t ws_size,
                              hipStream_t stream) {
    const float* x    = (const float*)d_in[0];
    const float* wqkv = (const float*)d_in[1];
    const float* w1   = (const float*)d_in[2];
    const float* w2   = (const float*)d_in[3];
    float* out = (float*)d_out;

    char* ws = (char*)d_ws;
    float* mix            = (float*)(ws);                 // 393216 B
    float* wgt_list       = (float*)(ws + 393216);        // 131072 B
    int*   tok_list       = (int*)  (ws + 524288);        // 131072 B
    int*   cnt            = (int*)  (ws + 655360);        // 128 B
    unsigned short* gu    = (unsigned short*)(ws + 655488); // 2048*2048*2 = 8388608 B

    hipMemsetAsync(cnt, 0, 128, stream);
    hipMemsetAsync(out, 0, (size_t)out_size * sizeof(float), stream);

    k_router_mix<<<TT, 128, 0, stream>>>(x, wqkv, mix);
    k_router_attn<<<TT, 64, 0, stream>>>(mix, cnt, tok_list, wgt_list);
    k_gemm1<<<dim3(2 * II / 128, EE, 8), 256, 0, stream>>>(x, w1, cnt, tok_list, gu);
    k_gemm2<<<dim3(HH / 128, EE, 8), 256, 0, stream>>>(gu, w2, cnt, tok_list, wgt_list, out);
}

// Round 3
// 324.067 us; speedup vs baseline: 3.8646x; 1.0647x over previous
//
#include <hip/hip_runtime.h>
#include <hip/hip_bf16.h>
#include <math.h>

#define TT 1024
#define HH 2048
#define EE 32
#define II 1024
#define BK 64
#define SA 72   // LDS row stride in bf16 elems (64 + 8 pad -> 2-way bank alias only)

typedef __attribute__((ext_vector_type(8))) short bf16x8;
typedef __attribute__((ext_vector_type(8))) unsigned short ushort8;
typedef __attribute__((ext_vector_type(4))) float f32x4;

__device__ __forceinline__ unsigned short f2b(float f) {
    union { float f; unsigned u; } c; c.f = f;
    unsigned r = c.u + 0x7FFFu + ((c.u >> 16) & 1u);   // RNE to bf16
    return (unsigned short)(r >> 16);
}
__device__ __forceinline__ float b2f(unsigned short u) {
    union { unsigned u; float f; } c; c.u = ((unsigned)u) << 16;
    return c.f;
}
__device__ __forceinline__ unsigned cvtpk(float lo, float hi) {
    unsigned r;
    asm("v_cvt_pk_bf16_f32 %0, %1, %2" : "=v"(r) : "v"(lo), "v"(hi));
    return r;
}
__device__ __forceinline__ ushort8 pack8(float4 a, float4 b) {
    union { unsigned u[4]; ushort8 s; } cv;
    cv.u[0] = cvtpk(a.x, a.y); cv.u[1] = cvtpk(a.z, a.w);
    cv.u[2] = cvtpk(b.x, b.y); cv.u[3] = cvtpk(b.z, b.w);
    return cv.s;
}

// ---------------- router: mix = x @ w_qkv^T  [T, 96] ----------------
__global__ void k_router_mix(const float* __restrict__ x,
                             const float* __restrict__ wqkv,
                             float* __restrict__ mix) {
    __shared__ float xs[HH];
    const int t = blockIdx.x;
    const float4* xr = (const float4*)(x + (size_t)t * HH);
    float4* xs4 = (float4*)xs;
    for (int i = threadIdx.x; i < HH / 4; i += blockDim.x) xs4[i] = xr[i];
    __syncthreads();
    const int j = threadIdx.x;
    if (j < 3 * EE) {
        const float4* wr = (const float4*)(wqkv + (size_t)j * HH);
        float a0 = 0.f, a1 = 0.f, a2 = 0.f, a3 = 0.f;
        for (int i = 0; i < HH / 4; i += 4) {
            float4 w0 = wr[i],     x0 = xs4[i];
            float4 w1 = wr[i + 1], x1 = xs4[i + 1];
            float4 w2 = wr[i + 2], x2 = xs4[i + 2];
            float4 w3 = wr[i + 3], x3 = xs4[i + 3];
            a0 += x0.x * w0.x + x0.y * w0.y + x0.z * w0.z + x0.w * w0.w;
            a1 += x1.x * w1.x + x1.y * w1.y + x1.z * w1.z + x1.w * w1.w;
            a2 += x2.x * w2.x + x2.y * w2.y + x2.z * w2.z + x2.w * w2.w;
            a3 += x3.x * w3.x + x3.y * w3.y + x3.z * w3.z + x3.w * w3.w;
        }
        mix[t * 96 + j] = (a0 + a1) + (a2 + a3);
    }
}

// ---------------- router: attention logits + top-2 + scatter ----------------
__global__ void k_router_attn(const float* __restrict__ mix,
                              int* __restrict__ cnt,
                              int* __restrict__ tok_list,
                              float* __restrict__ wgt_list) {
    const int t = blockIdx.x;
    __shared__ float kk[EE], vv[EE], lg[EE];
    const int lane = threadIdx.x;
    if (lane < EE) {
        kk[lane] = mix[t * 96 + EE + lane];
        vv[lane] = mix[t * 96 + 2 * EE + lane];
    }
    __syncthreads();
    if (lane < EE) {
        float q = mix[t * 96 + lane];
        float m = -1e30f;
        for (int f = 0; f < EE; ++f) m = fmaxf(m, q * kk[f]);
        float s = 0.f, a = 0.f;
        for (int f = 0; f < EE; ++f) {
            float ex = expf(q * kk[f] - m);
            s += ex;
            a += ex * vv[f];
        }
        lg[lane] = a / s;
    }
    __syncthreads();
    if (lane == 0) {
        int b0 = 0; float v0 = lg[0];
        for (int e2 = 1; e2 < EE; ++e2)
            if (lg[e2] > v0) { v0 = lg[e2]; b0 = e2; }
        int b1 = -1; float v1 = -1e30f;
        for (int e2 = 0; e2 < EE; ++e2)
            if (e2 != b0 && lg[e2] > v1) { v1 = lg[e2]; b1 = e2; }
        float ex = expf(v1 - v0);
        float w0 = 1.f / (1.f + ex);
        float w1 = ex / (1.f + ex);
        int p0 = atomicAdd(&cnt[b0], 1);
        tok_list[b0 * TT + p0] = t * 2 + 0;
        wgt_list[b0 * TT + p0] = w0;
        int p1 = atomicAdd(&cnt[b1], 1);
        tok_list[b1 * TT + p1] = t * 2 + 1;
        wgt_list[b1 * TT + p1] = w1;
    }
}

// ---------------- gemm1: gu[entry, 0:2I] = x[tok] @ w1[e]^T  (bf16 MFMA, 2-phase reg-staged) ----------------
__global__ __launch_bounds__(256, 2) void k_gemm1(
    const float* __restrict__ x, const float* __restrict__ w1,
    const int* __restrict__ cnt, const int* __restrict__ tok_list,
    unsigned short* __restrict__ gu) {
    const int e = blockIdx.y;
    const int M = cnt[e];
    const int m0 = blockIdx.z * 128;
    if (m0 >= M) return;
    const int n0 = blockIdx.x * 128;

    __shared__ __align__(16) unsigned short As[128 * SA];
    __shared__ __align__(16) unsigned short Bs[128 * SA];
    __shared__ int ts[128];

    const int tid = threadIdx.x;
    if (tid < 128) {
        int mr = m0 + tid;
        ts[tid] = (mr < M) ? tok_list[e * TT + mr] : -1;
    }
    __syncthreads();

    const float* w1e = w1 + (size_t)e * (2 * II) * HH;
    const int wid = tid >> 6;
    const int lane = tid & 63;
    const int wm = wid >> 1, wn = wid & 1;
    const int fr = lane & 15;
    const int kg = lane >> 4;
    const int srow = tid >> 3;          // staging row this thread owns
    const int sc8 = (tid & 7) * 8;      // staging col offset (8 floats)

    f32x4 acc[4][4];
#pragma unroll
    for (int i = 0; i < 4; ++i)
#pragma unroll
        for (int j = 0; j < 4; ++j) acc[i][j] = (f32x4){0.f, 0.f, 0.f, 0.f};

    float4 pa[8], pb[8];
    const float4 f4z = {0.f, 0.f, 0.f, 0.f};
    // prologue: load tile k0=0 into regs
#pragma unroll
    for (int q = 0; q < 4; ++q) {
        int row = srow + q * 32;
        int entry = ts[row];
        if (entry >= 0) {
            const float* s = x + (size_t)(entry >> 1) * HH + sc8;
            pa[2 * q] = ((const float4*)s)[0]; pa[2 * q + 1] = ((const float4*)s)[1];
        } else { pa[2 * q] = f4z; pa[2 * q + 1] = f4z; }
        const float* sb = w1e + (size_t)(n0 + row) * HH + sc8;
        pb[2 * q] = ((const float4*)sb)[0]; pb[2 * q + 1] = ((const float4*)sb)[1];
    }

    for (int k0 = 0; k0 < HH; k0 += BK) {
        __syncthreads();
        // write phase: cvt staged regs -> LDS
#pragma unroll
        for (int q = 0; q < 4; ++q) {
            int row = srow + q * 32;
            *(ushort8*)&As[row * SA + sc8] = pack8(pa[2 * q], pa[2 * q + 1]);
            *(ushort8*)&Bs[row * SA + sc8] = pack8(pb[2 * q], pb[2 * q + 1]);
        }
        __syncthreads();
        // issue next tile's loads (in flight across the MFMA phase)
        if (k0 + BK < HH) {
            int kn = k0 + BK;
#pragma unroll
            for (int q = 0; q < 4; ++q) {
                int row = srow + q * 32;
                int entry = ts[row];
                if (entry >= 0) {
                    const float* s = x + (size_t)(entry >> 1) * HH + kn + sc8;
                    pa[2 * q] = ((const float4*)s)[0]; pa[2 * q + 1] = ((const float4*)s)[1];
                } else { pa[2 * q] = f4z; pa[2 * q + 1] = f4z; }
                const float* sb = w1e + (size_t)(n0 + row) * HH + kn + sc8;
                pb[2 * q] = ((const float4*)sb)[0]; pb[2 * q + 1] = ((const float4*)sb)[1];
            }
        }
        // compute phase
#pragma unroll
        for (int kh = 0; kh < 2; ++kh) {
            const int kb = kh * 32 + kg * 8;
            bf16x8 a[4], b[4];
#pragma unroll
            for (int i = 0; i < 4; ++i)
                a[i] = *(const bf16x8*)&As[(wm * 64 + i * 16 + fr) * SA + kb];
#pragma unroll
            for (int j = 0; j < 4; ++j)
                b[j] = *(const bf16x8*)&Bs[(wn * 64 + j * 16 + fr) * SA + kb];
#pragma unroll
            for (int i = 0; i < 4; ++i)
#pragma unroll
                for (int j = 0; j < 4; ++j)
                    acc[i][j] = __builtin_amdgcn_mfma_f32_16x16x32_bf16(a[i], b[j], acc[i][j], 0, 0, 0);
        }
    }
    // epilogue: store bf16 raw gate/up
#pragma unroll
    for (int mi = 0; mi < 4; ++mi) {
#pragma unroll
        for (int reg = 0; reg < 4; ++reg) {
            int m = wm * 64 + mi * 16 + kg * 4 + reg;
            int entry = ts[m];
            if (entry < 0) continue;
            unsigned short* dst = gu + (size_t)entry * (2 * II) + n0 + wn * 64;
#pragma unroll
            for (int ni = 0; ni < 4; ++ni)
                dst[ni * 16 + fr] = f2b(acc[mi][ni][reg]);
        }
    }
}

// ---------------- gemm2: po[entry] = (silu(gate)*up*w) @ w2[e]^T  (bf16 MFMA, 2-phase reg-staged) ----------------
__global__ __launch_bounds__(256, 2) void k_gemm2(
    const unsigned short* __restrict__ gu, const float* __restrict__ w2,
    const int* __restrict__ cnt, const int* __restrict__ tok_list,
    const float* __restrict__ wgt_list, float* __restrict__ po) {
    const int e = blockIdx.y;
    const int M = cnt[e];
    const int m0 = blockIdx.z * 128;
    if (m0 >= M) return;
    const int n0 = blockIdx.x * 128;

    __shared__ __align__(16) unsigned short As[128 * SA];
    __shared__ __align__(16) unsigned short Bs[128 * SA];
    __shared__ int ts[128];
    __shared__ float tw[128];

    const int tid = threadIdx.x;
    if (tid < 128) {
        int mr = m0 + tid;
        if (mr < M) {
            ts[tid] = tok_list[e * TT + mr];
            tw[tid] = wgt_list[e * TT + mr];
        } else { ts[tid] = -1; tw[tid] = 0.f; }
    }
    __syncthreads();

    const float* w2e = w2 + (size_t)e * HH * II;
    const int wid = tid >> 6;
    const int lane = tid & 63;
    const int wm = wid >> 1, wn = wid & 1;
    const int fr = lane & 15;
    const int kg = lane >> 4;
    const int srow = tid >> 3;
    const int sc8 = (tid & 7) * 8;

    f32x4 acc[4][4];
#pragma unroll
    for (int i = 0; i < 4; ++i)
#pragma unroll
        for (int j = 0; j < 4; ++j) acc[i][j] = (f32x4){0.f, 0.f, 0.f, 0.f};

    ushort8 pg[4], pu[4];
    float4 pb[8];
    const ushort8 u8z = {0, 0, 0, 0, 0, 0, 0, 0};
    // prologue
#pragma unroll
    for (int q = 0; q < 4; ++q) {
        int row = srow + q * 32;
        int entry = ts[row];
        if (entry >= 0) {
            pg[q] = *(const ushort8*)(gu + (size_t)entry * (2 * II) + sc8);
            pu[q] = *(const ushort8*)(gu + (size_t)entry * (2 * II) + II + sc8);
        } else { pg[q] = u8z; pu[q] = u8z; }
        const float* sb = w2e + (size_t)(n0 + row) * II + sc8;
        pb[2 * q] = ((const float4*)sb)[0]; pb[2 * q + 1] = ((const float4*)sb)[1];
    }

    for (int k0 = 0; k0 < II; k0 += BK) {
        __syncthreads();
        // write phase: A = silu(gate)*up*w  (bf16 in regs -> f32 -> bf16), B cvt
#pragma unroll
        for (int q = 0; q < 4; ++q) {
            int row = srow + q * 32;
            float w = tw[row];
            float4 lo, hi;
            {
                float s0[8];
#pragma unroll
                for (int j = 0; j < 8; ++j) {
                    float g = b2f((unsigned short)pg[q][j]);
                    float u = b2f((unsigned short)pu[q][j]);
                    s0[j] = (g / (1.f + __expf(-g))) * u * w;
                }
                lo = make_float4(s0[0], s0[1], s0[2], s0[3]);
                hi = make_float4(s0[4], s0[5], s0[6], s0[7]);
            }
            *(ushort8*)&As[row * SA + sc8] = pack8(lo, hi);
            *(ushort8*)&Bs[row * SA + sc8] = pack8(pb[2 * q], pb[2 * q + 1]);
        }
        __syncthreads();
        if (k0 + BK < II) {
            int kn = k0 + BK;
#pragma unroll
            for (int q = 0; q < 4; ++q) {
                int row = srow + q * 32;
                int entry = ts[row];
                if (entry >= 0) {
                    pg[q] = *(const ushort8*)(gu + (size_t)entry * (2 * II) + kn + sc8);
                    pu[q] = *(const ushort8*)(gu + (size_t)entry * (2 * II) + II + kn + sc8);
                } else { pg[q] = u8z; pu[q] = u8z; }
                const float* sb = w2e + (size_t)(n0 + row) * II + kn + sc8;
                pb[2 * q] = ((const float4*)sb)[0]; pb[2 * q + 1] = ((const float4*)sb)[1];
            }
        }
#pragma unroll
        for (int kh = 0; kh < 2; ++kh) {
            const int kb = kh * 32 + kg * 8;
            bf16x8 a[4], b[4];
#pragma unroll
            for (int i = 0; i < 4; ++i)
                a[i] = *(const bf16x8*)&As[(wm * 64 + i * 16 + fr) * SA + kb];
#pragma unroll
            for (int j = 0; j < 4; ++j)
                b[j] = *(const bf16x8*)&Bs[(wn * 64 + j * 16 + fr) * SA + kb];
#pragma unroll
            for (int i = 0; i < 4; ++i)
#pragma unroll
                for (int j = 0; j < 4; ++j)
                    acc[i][j] = __builtin_amdgcn_mfma_f32_16x16x32_bf16(a[i], b[j], acc[i][j], 0, 0, 0);
        }
    }
    // epilogue: store fp32 partials per entry (each entry written exactly once)
#pragma unroll
    for (int mi = 0; mi < 4; ++mi) {
#pragma unroll
        for (int reg = 0; reg < 4; ++reg) {
            int m = wm * 64 + mi * 16 + kg * 4 + reg;
            int entry = ts[m];
            if (entry < 0) continue;
            float* op = po + (size_t)entry * HH + n0 + wn * 64;
#pragma unroll
            for (int ni = 0; ni < 4; ++ni)
                op[ni * 16 + fr] = acc[mi][ni][reg];
        }
    }
}

// ---------------- combine: out[t] = po[2t] + po[2t+1] ----------------
__global__ __launch_bounds__(256) void k_combine(const float* __restrict__ po,
                                                 float* __restrict__ out) {
    int i = blockIdx.x * 256 + threadIdx.x;     // over T * H/4
    int t = i / (HH / 4);
    int c = i % (HH / 4);
    float4 a = ((const float4*)(po + (size_t)(2 * t) * HH))[c];
    float4 b = ((const float4*)(po + (size_t)(2 * t + 1) * HH))[c];
    float4 r = make_float4(a.x + b.x, a.y + b.y, a.z + b.z, a.w + b.w);
    ((float4*)(out + (size_t)t * HH))[c] = r;
}

extern "C" void kernel_launch(void* const* d_in, const int* in_sizes, int n_in,
                              void* d_out, int out_size, void* d_ws, size_t ws_size,
                              hipStream_t stream) {
    const float* x    = (const float*)d_in[0];
    const float* wqkv = (const float*)d_in[1];
    const float* w1   = (const float*)d_in[2];
    const float* w2   = (const float*)d_in[3];
    float* out = (float*)d_out;

    char* ws = (char*)d_ws;
    float* mix            = (float*)(ws);                     // 393216 B
    float* wgt_list       = (float*)(ws + 393216);            // 131072 B
    int*   tok_list       = (int*)  (ws + 524288);            // 131072 B
    int*   cnt            = (int*)  (ws + 655360);            // 128 B
    unsigned short* gu    = (unsigned short*)(ws + 655488);   // 8388608 B
    float* po             = (float*)(ws + 9044096);           // 16777216 B

    hipMemsetAsync(cnt, 0, 128, stream);

    k_router_mix<<<TT, 128, 0, stream>>>(x, wqkv, mix);
    k_router_attn<<<TT, 64, 0, stream>>>(mix, cnt, tok_list, wgt_list);
    k_gemm1<<<dim3(2 * II / 128, EE, 8), 256, 0, stream>>>(x, w1, cnt, tok_list, gu);
    k_gemm2<<<dim3(HH / 128, EE, 8), 256, 0, stream>>>(gu, w2, cnt, tok_list, wgt_list, po);
    k_combine<<<TT * HH / 4 / 256, 256, 0, stream>>>(po, out);
}

// Round 4
// 247.417 us; speedup vs baseline: 5.0619x; 1.3098x over previous
//
#include <hip/hip_runtime.h>
#include <hip/hip_bf16.h>
#include <math.h>

#define TT 1024
#define HH 2048
#define EE 32
#define II 1024
#define BK 64
#define SA 72   // LDS row stride in bf16 elems (64 + 8 pad -> 2-way bank alias only)
#define KSP 32  // router split-K chunks (K-chunk = 64)
#define MB 64   // router tokens per block

typedef __attribute__((ext_vector_type(8))) short bf16x8;
typedef __attribute__((ext_vector_type(8))) unsigned short ushort8;
typedef __attribute__((ext_vector_type(4))) float f32x4;

__device__ __forceinline__ unsigned short f2b(float f) {
    union { float f; unsigned u; } c; c.f = f;
    unsigned r = c.u + 0x7FFFu + ((c.u >> 16) & 1u);   // RNE to bf16
    return (unsigned short)(r >> 16);
}
__device__ __forceinline__ float b2f(unsigned short u) {
    union { unsigned u; float f; } c; c.u = ((unsigned)u) << 16;
    return c.f;
}
__device__ __forceinline__ unsigned cvtpk(float lo, float hi) {
    unsigned r;
    asm("v_cvt_pk_bf16_f32 %0, %1, %2" : "=v"(r) : "v"(lo), "v"(hi));
    return r;
}
__device__ __forceinline__ ushort8 pack8(float4 a, float4 b) {
    union { unsigned u[4]; ushort8 s; } cv;
    cv.u[0] = cvtpk(a.x, a.y); cv.u[1] = cvtpk(a.z, a.w);
    cv.u[2] = cvtpk(b.x, b.y); cv.u[3] = cvtpk(b.z, b.w);
    return cv.s;
}

// ---------------- router mix: split-K tiled fp32 GEMM ----------------
// mixp[ks][t][j] partial of x[t,:] . wqkv[j,:] over K-chunk ks
// grid (TT/MB=16, KSP=32), block 256
__global__ __launch_bounds__(256) void k_mix(const float* __restrict__ x,
                                             const float* __restrict__ wqkv,
                                             float* __restrict__ mixp) {
    __shared__ float xs[MB][68];
    __shared__ float ws_[96][68];
    const int tm0 = blockIdx.x * MB;
    const int k0 = blockIdx.y * 64;
    const int tid = threadIdx.x;
#pragma unroll
    for (int q = 0; q < 4; ++q) {          // xs: 64 rows x 64 floats
        int p = tid + q * 256;
        int row = p >> 4, c4 = (p & 15) * 4;
        *(float4*)&xs[row][c4] = *(const float4*)(x + (size_t)(tm0 + row) * HH + k0 + c4);
    }
#pragma unroll
    for (int q = 0; q < 6; ++q) {          // ws: 96 rows x 64 floats
        int p = tid + q * 256;
        int row = p >> 4, c4 = (p & 15) * 4;
        *(float4*)&ws_[row][c4] = *(const float4*)(wqkv + (size_t)row * HH + k0 + c4);
    }
    __syncthreads();
    const int tg = tid >> 4, cg = tid & 15;   // 4 tokens x 6 cols per thread
    float acc[4][6];
#pragma unroll
    for (int i = 0; i < 4; ++i)
#pragma unroll
        for (int c = 0; c < 6; ++c) acc[i][c] = 0.f;
    for (int k = 0; k < 64; k += 4) {
        float4 xv[4], wv[6];
#pragma unroll
        for (int i = 0; i < 4; ++i) xv[i] = *(const float4*)&xs[tg * 4 + i][k];
#pragma unroll
        for (int c = 0; c < 6; ++c) wv[c] = *(const float4*)&ws_[cg * 6 + c][k];
#pragma unroll
        for (int i = 0; i < 4; ++i)
#pragma unroll
            for (int c = 0; c < 6; ++c)
                acc[i][c] += xv[i].x * wv[c].x + xv[i].y * wv[c].y +
                             xv[i].z * wv[c].z + xv[i].w * wv[c].w;
    }
    float* dst = mixp + ((size_t)blockIdx.y * TT + tm0) * 96;
#pragma unroll
    for (int i = 0; i < 4; ++i)
#pragma unroll
        for (int c = 0; c < 6; ++c)
            dst[(tg * 4 + i) * 96 + cg * 6 + c] = acc[i][c];
}

// ---------------- router: reduce partials + attention + top-2 + scatter ----------------
__global__ void k_router_attn(const float* __restrict__ mixp,
                              int* __restrict__ cnt,
                              int* __restrict__ tok_list,
                              float* __restrict__ wgt_list) {
    const int t = blockIdx.x;
    __shared__ float mrow[96];
    __shared__ float lg[EE];
    const int tid = threadIdx.x;
    if (tid < 96) {
        float s = 0.f;
        for (int sp = 0; sp < KSP; ++sp)          // fixed order -> deterministic
            s += mixp[((size_t)sp * TT + t) * 96 + tid];
        mrow[tid] = s;
    }
    __syncthreads();
    if (tid < EE) {
        float q = mrow[tid];
        float m = -1e30f;
        for (int f = 0; f < EE; ++f) m = fmaxf(m, q * mrow[32 + f]);
        float s = 0.f, a = 0.f;
        for (int f = 0; f < EE; ++f) {
            float ex = expf(q * mrow[32 + f] - m);
            s += ex;
            a += ex * mrow[64 + f];
        }
        lg[tid] = a / s;
    }
    __syncthreads();
    if (tid == 0) {
        int b0 = 0; float v0 = lg[0];
        for (int e2 = 1; e2 < EE; ++e2)
            if (lg[e2] > v0) { v0 = lg[e2]; b0 = e2; }
        int b1 = -1; float v1 = -1e30f;
        for (int e2 = 0; e2 < EE; ++e2)
            if (e2 != b0 && lg[e2] > v1) { v1 = lg[e2]; b1 = e2; }
        float ex = expf(v1 - v0);
        float w0 = 1.f / (1.f + ex);
        float w1 = ex / (1.f + ex);
        int p0 = atomicAdd(&cnt[b0], 1);
        tok_list[b0 * TT + p0] = t * 2 + 0;
        wgt_list[b0 * TT + p0] = w0;
        int p1 = atomicAdd(&cnt[b1], 1);
        tok_list[b1 * TT + p1] = t * 2 + 1;
        wgt_list[b1 * TT + p1] = w1;
    }
}

// ---------------- gemm1: gu[entry, 0:2I] = x[tok] @ w1[e]^T  (bf16 MFMA, 2-phase reg-staged) ----------------
__global__ __launch_bounds__(256, 2) void k_gemm1(
    const float* __restrict__ x, const float* __restrict__ w1,
    const int* __restrict__ cnt, const int* __restrict__ tok_list,
    unsigned short* __restrict__ gu) {
    const int e = blockIdx.y;
    const int M = cnt[e];
    const int m0 = blockIdx.z * 128;
    if (m0 >= M) return;
    const int n0 = blockIdx.x * 128;

    __shared__ __align__(16) unsigned short As[128 * SA];
    __shared__ __align__(16) unsigned short Bs[128 * SA];
    __shared__ int ts[128];

    const int tid = threadIdx.x;
    if (tid < 128) {
        int mr = m0 + tid;
        ts[tid] = (mr < M) ? tok_list[e * TT + mr] : -1;
    }
    __syncthreads();

    const float* w1e = w1 + (size_t)e * (2 * II) * HH;
    const int wid = tid >> 6;
    const int lane = tid & 63;
    const int wm = wid >> 1, wn = wid & 1;
    const int fr = lane & 15;
    const int kg = lane >> 4;
    const int srow = tid >> 3;          // staging row this thread owns
    const int sc8 = (tid & 7) * 8;      // staging col offset (8 floats)

    f32x4 acc[4][4];
#pragma unroll
    for (int i = 0; i < 4; ++i)
#pragma unroll
        for (int j = 0; j < 4; ++j) acc[i][j] = (f32x4){0.f, 0.f, 0.f, 0.f};

    float4 pa[8], pb[8];
    const float4 f4z = {0.f, 0.f, 0.f, 0.f};
#pragma unroll
    for (int q = 0; q < 4; ++q) {
        int row = srow + q * 32;
        int entry = ts[row];
        if (entry >= 0) {
            const float* s = x + (size_t)(entry >> 1) * HH + sc8;
            pa[2 * q] = ((const float4*)s)[0]; pa[2 * q + 1] = ((const float4*)s)[1];
        } else { pa[2 * q] = f4z; pa[2 * q + 1] = f4z; }
        const float* sb = w1e + (size_t)(n0 + row) * HH + sc8;
        pb[2 * q] = ((const float4*)sb)[0]; pb[2 * q + 1] = ((const float4*)sb)[1];
    }

    for (int k0 = 0; k0 < HH; k0 += BK) {
        __syncthreads();
#pragma unroll
        for (int q = 0; q < 4; ++q) {
            int row = srow + q * 32;
            *(ushort8*)&As[row * SA + sc8] = pack8(pa[2 * q], pa[2 * q + 1]);
            *(ushort8*)&Bs[row * SA + sc8] = pack8(pb[2 * q], pb[2 * q + 1]);
        }
        __syncthreads();
        if (k0 + BK < HH) {
            int kn = k0 + BK;
#pragma unroll
            for (int q = 0; q < 4; ++q) {
                int row = srow + q * 32;
                int entry = ts[row];
                if (entry >= 0) {
                    const float* s = x + (size_t)(entry >> 1) * HH + kn + sc8;
                    pa[2 * q] = ((const float4*)s)[0]; pa[2 * q + 1] = ((const float4*)s)[1];
                } else { pa[2 * q] = f4z; pa[2 * q + 1] = f4z; }
                const float* sb = w1e + (size_t)(n0 + row) * HH + kn + sc8;
                pb[2 * q] = ((const float4*)sb)[0]; pb[2 * q + 1] = ((const float4*)sb)[1];
            }
        }
#pragma unroll
        for (int kh = 0; kh < 2; ++kh) {
            const int kb = kh * 32 + kg * 8;
            bf16x8 a[4], b[4];
#pragma unroll
            for (int i = 0; i < 4; ++i)
                a[i] = *(const bf16x8*)&As[(wm * 64 + i * 16 + fr) * SA + kb];
#pragma unroll
            for (int j = 0; j < 4; ++j)
                b[j] = *(const bf16x8*)&Bs[(wn * 64 + j * 16 + fr) * SA + kb];
#pragma unroll
            for (int i = 0; i < 4; ++i)
#pragma unroll
                for (int j = 0; j < 4; ++j)
                    acc[i][j] = __builtin_amdgcn_mfma_f32_16x16x32_bf16(a[i], b[j], acc[i][j], 0, 0, 0);
        }
    }
#pragma unroll
    for (int mi = 0; mi < 4; ++mi) {
#pragma unroll
        for (int reg = 0; reg < 4; ++reg) {
            int m = wm * 64 + mi * 16 + kg * 4 + reg;
            int entry = ts[m];
            if (entry < 0) continue;
            unsigned short* dst = gu + (size_t)entry * (2 * II) + n0 + wn * 64;
#pragma unroll
            for (int ni = 0; ni < 4; ++ni)
                dst[ni * 16 + fr] = f2b(acc[mi][ni][reg]);
        }
    }
}

// ---------------- gemm2: po[entry] = (silu(gate)*up*w) @ w2[e]^T  (bf16 MFMA, 2-phase reg-staged) ----------------
__global__ __launch_bounds__(256, 2) void k_gemm2(
    const unsigned short* __restrict__ gu, const float* __restrict__ w2,
    const int* __restrict__ cnt, const int* __restrict__ tok_list,
    const float* __restrict__ wgt_list, float* __restrict__ po) {
    const int e = blockIdx.y;
    const int M = cnt[e];
    const int m0 = blockIdx.z * 128;
    if (m0 >= M) return;
    const int n0 = blockIdx.x * 128;

    __shared__ __align__(16) unsigned short As[128 * SA];
    __shared__ __align__(16) unsigned short Bs[128 * SA];
    __shared__ int ts[128];
    __shared__ float tw[128];

    const int tid = threadIdx.x;
    if (tid < 128) {
        int mr = m0 + tid;
        if (mr < M) {
            ts[tid] = tok_list[e * TT + mr];
            tw[tid] = wgt_list[e * TT + mr];
        } else { ts[tid] = -1; tw[tid] = 0.f; }
    }
    __syncthreads();

    const float* w2e = w2 + (size_t)e * HH * II;
    const int wid = tid >> 6;
    const int lane = tid & 63;
    const int wm = wid >> 1, wn = wid & 1;
    const int fr = lane & 15;
    const int kg = lane >> 4;
    const int srow = tid >> 3;
    const int sc8 = (tid & 7) * 8;

    f32x4 acc[4][4];
#pragma unroll
    for (int i = 0; i < 4; ++i)
#pragma unroll
        for (int j = 0; j < 4; ++j) acc[i][j] = (f32x4){0.f, 0.f, 0.f, 0.f};

    ushort8 pg[4], pu[4];
    float4 pb[8];
    const ushort8 u8z = {0, 0, 0, 0, 0, 0, 0, 0};
#pragma unroll
    for (int q = 0; q < 4; ++q) {
        int row = srow + q * 32;
        int entry = ts[row];
        if (entry >= 0) {
            pg[q] = *(const ushort8*)(gu + (size_t)entry * (2 * II) + sc8);
            pu[q] = *(const ushort8*)(gu + (size_t)entry * (2 * II) + II + sc8);
        } else { pg[q] = u8z; pu[q] = u8z; }
        const float* sb = w2e + (size_t)(n0 + row) * II + sc8;
        pb[2 * q] = ((const float4*)sb)[0]; pb[2 * q + 1] = ((const float4*)sb)[1];
    }

    for (int k0 = 0; k0 < II; k0 += BK) {
        __syncthreads();
#pragma unroll
        for (int q = 0; q < 4; ++q) {
            int row = srow + q * 32;
            float w = tw[row];
            float4 lo, hi;
            {
                float s0[8];
#pragma unroll
                for (int j = 0; j < 8; ++j) {
                    float g = b2f((unsigned short)pg[q][j]);
                    float u = b2f((unsigned short)pu[q][j]);
                    s0[j] = (g / (1.f + __expf(-g))) * u * w;
                }
                lo = make_float4(s0[0], s0[1], s0[2], s0[3]);
                hi = make_float4(s0[4], s0[5], s0[6], s0[7]);
            }
            *(ushort8*)&As[row * SA + sc8] = pack8(lo, hi);
            *(ushort8*)&Bs[row * SA + sc8] = pack8(pb[2 * q], pb[2 * q + 1]);
        }
        __syncthreads();
        if (k0 + BK < II) {
            int kn = k0 + BK;
#pragma unroll
            for (int q = 0; q < 4; ++q) {
                int row = srow + q * 32;
                int entry = ts[row];
                if (entry >= 0) {
                    pg[q] = *(const ushort8*)(gu + (size_t)entry * (2 * II) + kn + sc8);
                    pu[q] = *(const ushort8*)(gu + (size_t)entry * (2 * II) + II + kn + sc8);
                } else { pg[q] = u8z; pu[q] = u8z; }
                const float* sb = w2e + (size_t)(n0 + row) * II + kn + sc8;
                pb[2 * q] = ((const float4*)sb)[0]; pb[2 * q + 1] = ((const float4*)sb)[1];
            }
        }
#pragma unroll
        for (int kh = 0; kh < 2; ++kh) {
            const int kb = kh * 32 + kg * 8;
            bf16x8 a[4], b[4];
#pragma unroll
            for (int i = 0; i < 4; ++i)
                a[i] = *(const bf16x8*)&As[(wm * 64 + i * 16 + fr) * SA + kb];
#pragma unroll
            for (int j = 0; j < 4; ++j)
                b[j] = *(const bf16x8*)&Bs[(wn * 64 + j * 16 + fr) * SA + kb];
#pragma unroll
            for (int i = 0; i < 4; ++i)
#pragma unroll
                for (int j = 0; j < 4; ++j)
                    acc[i][j] = __builtin_amdgcn_mfma_f32_16x16x32_bf16(a[i], b[j], acc[i][j], 0, 0, 0);
        }
    }
#pragma unroll
    for (int mi = 0; mi < 4; ++mi) {
#pragma unroll
        for (int reg = 0; reg < 4; ++reg) {
            int m = wm * 64 + mi * 16 + kg * 4 + reg;
            int entry = ts[m];
            if (entry < 0) continue;
            float* op = po + (size_t)entry * HH + n0 + wn * 64;
#pragma unroll
            for (int ni = 0; ni < 4; ++ni)
                op[ni * 16 + fr] = acc[mi][ni][reg];
        }
    }
}

// ---------------- combine: out[t] = po[2t] + po[2t+1] ----------------
__global__ __launch_bounds__(256) void k_combine(const float* __restrict__ po,
                                                 float* __restrict__ out) {
    int i = blockIdx.x * 256 + threadIdx.x;     // over T * H/4
    int t = i / (HH / 4);
    int c = i % (HH / 4);
    float4 a = ((const float4*)(po + (size_t)(2 * t) * HH))[c];
    float4 b = ((const float4*)(po + (size_t)(2 * t + 1) * HH))[c];
    float4 r = make_float4(a.x + b.x, a.y + b.y, a.z + b.z, a.w + b.w);
    ((float4*)(out + (size_t)t * HH))[c] = r;
}

extern "C" void kernel_launch(void* const* d_in, const int* in_sizes, int n_in,
                              void* d_out, int out_size, void* d_ws, size_t ws_size,
                              hipStream_t stream) {
    const float* x    = (const float*)d_in[0];
    const float* wqkv = (const float*)d_in[1];
    const float* w1   = (const float*)d_in[2];
    const float* w2   = (const float*)d_in[3];
    float* out = (float*)d_out;

    char* ws = (char*)d_ws;
    float* mixp           = (float*)(ws);                      // 32*1024*96*4 = 12582912 B
    float* wgt_list       = (float*)(ws + 12582912);           // 131072 B
    int*   tok_list       = (int*)  (ws + 12714 * 1000 - 16);  // placeholder (overwritten below)
    tok_list              = (int*)  (ws + 12713984);           // 131072 B
    int*   cnt            = (int*)  (ws + 12845056);           // 128 B
    unsigned short* gu    = (unsigned short*)(ws + 12845184);  // 8388608 B
    float* po             = (float*)(ws + 21233792);           // 16777216 B

    hipMemsetAsync(cnt, 0, 128, stream);

    k_mix<<<dim3(TT / MB, KSP), 256, 0, stream>>>(x, wqkv, mixp);
    k_router_attn<<<TT, 128, 0, stream>>>(mixp, cnt, tok_list, wgt_list);
    k_gemm1<<<dim3(2 * II / 128, EE, 8), 256, 0, stream>>>(x, w1, cnt, tok_list, gu);
    k_gemm2<<<dim3(HH / 128, EE, 8), 256, 0, stream>>>(gu, w2, cnt, tok_list, wgt_list, po);
    k_combine<<<TT * HH / 4 / 256, 256, 0, stream>>>(po, out);
}